// Round 10
// baseline (308.647 us; speedup 1.0000x reference)
//
#include <hip/hip_runtime.h>
#include <hip/hip_bf16.h>

// QuantizedLinear: q = clip(round(lin/s)), s = max|lin|/127,
// lin = (x_q - x_zp) @ w_q^T + round(fp_bias / (w_scale*x_scale))
// Exact-integer path: x8 = x_q-128 (int8), w8 = w_q (int8),
// lin = x8@w8^T + (128 - x_zp[b])*rowsum(w) + qbias   (all int32, exact)
//
// GEMM (r10 = r9 with NT-builtin type fix): no-LDS fragment-direct design +
// LLC-locality fixes. r8 showed FETCH 548MB (11x re-fetch of the 48MB operand
// set): the 131MB lin store stream + requant traffic thrash the 256MB LLC, so
// operand loads miss to HBM (~900cyc) beyond dist-1 prefetch cover (~330cyc).
// Fixes: (1) nontemporal stores for lin_out + NT requant (output bypasses
// LLC), (2) tn-major block mapping so each XCD's resident blocks share B-
// panels (hot in its private L2) while A k-slabs stream.
// NOTE: __builtin_nontemporal_* requires scalar or ext_vector_type pointers
// (HIP_vector_type int4/float4 rejected) -- hence i32x4/f32x4 in requant.

typedef int i32x4 __attribute__((ext_vector_type(4)));
typedef float f32x4 __attribute__((ext_vector_type(4)));

// ---- pass 1a: x8t = fragment-ordered (x_q - 128); zero gmax ----
// block = (bm, kt): 512 thr, thread t=(m*64+l) -> 16B of sub-frag (bm,kt,m)
__global__ void conv_x_kernel(const float* __restrict__ xq, char* __restrict__ x8t,
                              int* gmax, int IN) {
    const int nkt = IN >> 6;
    const int bm = blockIdx.x / nkt, kt = blockIdx.x % nkt;
    const int t = threadIdx.x;
    const int m = t >> 6, l = t & 63;
    if (blockIdx.x == 0 && t == 0) *gmax = 0;
    const int row = bm * 128 + m * 16 + (l & 15);
    const int col = kt * 64 + (l >> 4) * 16;
    const float4* src = (const float4*)(xq + (size_t)row * IN + col);
    uint out[4];
    #pragma unroll
    for (int c = 0; c < 4; ++c) {
        float4 v = src[c];
        out[c] = (((int)v.x - 128) & 255) | ((((int)v.y - 128) & 255) << 8) |
                 ((((int)v.z - 128) & 255) << 16) | ((((int)v.w - 128) & 255) << 24);
    }
    *(uint4*)(x8t + ((size_t)blockIdx.x * 8 + m) * 1024 + l * 16) =
        make_uint4(out[0], out[1], out[2], out[3]);
}

// ---- pass 1b: w8t = fragment-ordered w_q ----
__global__ void conv_w_kernel(const float* __restrict__ wq, char* __restrict__ w8t,
                              int IN) {
    const int nkt = IN >> 6;
    const int bn = blockIdx.x / nkt, kt = blockIdx.x % nkt;
    const int t = threadIdx.x;
    const int m = t >> 6, l = t & 63;
    const int row = bn * 128 + m * 16 + (l & 15);
    const int col = kt * 64 + (l >> 4) * 16;
    const float4* src = (const float4*)(wq + (size_t)row * IN + col);
    uint out[4];
    #pragma unroll
    for (int c = 0; c < 4; ++c) {
        float4 v = src[c];
        out[c] = (((int)v.x) & 255) | ((((int)v.y) & 255) << 8) |
                 ((((int)v.z) & 255) << 16) | ((((int)v.w) & 255) << 24);
    }
    *(uint4*)(w8t + ((size_t)blockIdx.x * 8 + m) * 1024 + l * 16) =
        make_uint4(out[0], out[1], out[2], out[3]);
}

// ---- pass 1c: rowsum[r] = sum_k w8t row r (reads fragment layout) ----
__global__ void rowsum_kernel(const char* __restrict__ w8t, int* __restrict__ rowsum,
                              int IN) {
    const int r = blockIdx.x;
    const int bn = r >> 7, n = (r >> 4) & 7, rl = r & 15;
    const int t = threadIdx.x;          // 256
    const int nkt = IN >> 6;
    int sum = 0;
    for (int idx = t; idx < nkt * 4; idx += 256) {
        const int kt = idx >> 2, cs = idx & 3;
        const int* p = (const int*)(w8t + (((size_t)bn * nkt + kt) * 8 + n) * 1024
                                    + (size_t)((cs << 4) | rl) * 16);
        #pragma unroll
        for (int k = 0; k < 4; ++k) {
            const int u = p[k];
            sum += ((int)(u << 24) >> 24) + ((int)(u << 16) >> 24) +
                   ((int)(u << 8) >> 24) + (u >> 24);
        }
    }
    #pragma unroll
    for (int msk = 32; msk; msk >>= 1) sum += __shfl_xor(sum, msk, 64);
    __shared__ int wsum[4];
    if ((t & 63) == 0) wsum[t >> 6] = sum;
    __syncthreads();
    if (t == 0) rowsum[r] = wsum[0] + wsum[1] + wsum[2] + wsum[3];
}

// ---- pass 2: int8 GEMM, 128x128 tile, fragment-direct, no LDS/barriers ----
__global__ __launch_bounds__(256, 3) void gemm_i8_kernel(
    const char* __restrict__ x8t, const char* __restrict__ w8t,
    const int* __restrict__ w_rowsum,
    const float* __restrict__ x_scale, const float* __restrict__ x_zp,
    const float* __restrict__ fp_bias, const float* __restrict__ w_scale_p,
    int* __restrict__ lin_out, int* gmax, int N, int K) {
    __shared__ int s_bmax;
    const int t = threadIdx.x;
    const int w = t >> 6, l = t & 63;
    if (t == 0) s_bmax = 0;

    // T1: XCD-aware block swizzle (nwg = 2048, divisible by 8)
    const int nwg = gridDim.x;
    int swz = blockIdx.x;
    if ((nwg & 7) == 0) { const int cpx = nwg >> 3; swz = (swz & 7) * cpx + (swz >> 3); }
    // tn-major: consecutive swz (same XCD) share tn -> its B-panel stays hot
    // in that XCD's L2; A k-slabs stream.
    const int ntn = N >> 7;            // 32
    const int ntm = nwg / ntn;         // 64
    const int tm = swz % ntm, tn = swz / ntm;

    const int nt = K >> 6;             // 64B K-tiles (64); even
    const int lane_lo = l & 15, lane_hi = l >> 4;
    const int wm = w >> 1, wn = w & 1; // 2 x 2 wave grid

    // fragment bases: sub-frag (tile j, idx wm*4+m) at ((tm*nt + j)*8 + wm*4+m)*1024
    const char* pa = x8t + ((size_t)tm * nt * 8 + (size_t)wm * 4) * 1024 + l * 16;
    const char* pb = w8t + ((size_t)tn * nt * 8 + (size_t)wn * 4) * 1024 + l * 16;

    i32x4 acc[4][4] = {};
    i32x4 aA[4], bA[4], aB[4], bB[4];

    #define LDA(dst, j) { const char* p_ = pa + (size_t)(j) * 8192;                 \
        dst[0] = *(const i32x4*)(p_);        dst[1] = *(const i32x4*)(p_ + 1024);   \
        dst[2] = *(const i32x4*)(p_ + 2048); dst[3] = *(const i32x4*)(p_ + 3072); }
    #define LDB(dst, j) { const char* p_ = pb + (size_t)(j) * 8192;                 \
        dst[0] = *(const i32x4*)(p_);        dst[1] = *(const i32x4*)(p_ + 1024);   \
        dst[2] = *(const i32x4*)(p_ + 2048); dst[3] = *(const i32x4*)(p_ + 3072); }
    #define MFMA16(a_, b_) {                                                        \
        __builtin_amdgcn_s_setprio(1);                                              \
        _Pragma("unroll")                                                           \
        for (int m = 0; m < 4; ++m)                                                 \
            _Pragma("unroll")                                                       \
            for (int n = 0; n < 4; ++n)                                             \
                acc[m][n] = __builtin_amdgcn_mfma_i32_16x16x64_i8(a_[m], b_[n],     \
                                                                  acc[m][n], 0,0,0);\
        __builtin_amdgcn_s_setprio(0); }

    LDA(aA, 0); LDB(bA, 0);
    for (int j = 0; j < nt; j += 2) {
        LDA(aB, j + 1); LDB(bB, j + 1);    // prefetch odd tile
        MFMA16(aA, bA);
        if (j + 2 < nt) { LDA(aA, j + 2); LDB(bA, j + 2); }  // prefetch even tile
        MFMA16(aB, bB);
    }
    #undef LDA
    #undef LDB
    #undef MFMA16

    // ---- epilogue: lin = acc + z*rowsum + qbias; track max|lin|.
    // lin stores are NONTEMPORAL: keep the 131MB output stream from evicting
    // the 48MB operand set out of the LLC (r8: FETCH 548MB = 11x re-fetch).
    const float ws = *w_scale_p;
    const int rowg0 = tm * 128 + wm * 64 + lane_hi * 4;   // + m*16 + r
    const int colg0 = tn * 128 + wn * 64 + lane_lo;       // + n*16
    float fbws[4]; int wrs[4];
    #pragma unroll
    for (int n = 0; n < 4; ++n) {
        fbws[n] = fp_bias[colg0 + n * 16] / ws;
        wrs[n] = w_rowsum[colg0 + n * 16];
    }
    int lmax = 0;
    #pragma unroll
    for (int m = 0; m < 4; ++m) {
        #pragma unroll
        for (int r = 0; r < 4; ++r) {
            const int row = rowg0 + m * 16 + r;
            const float rxs = 1.0f / x_scale[row];
            const int zz = 128 - (int)x_zp[row];
            int* orow = lin_out + (size_t)row * N + colg0;
            #pragma unroll
            for (int n = 0; n < 4; ++n) {
                const int qb = (int)rintf(fbws[n] * rxs);
                const int lin = acc[m][n][r] + zz * wrs[n] + qb;
                const int a = lin < 0 ? -lin : lin;
                lmax = a > lmax ? a : lmax;
                __builtin_nontemporal_store(lin, orow + n * 16);
            }
        }
    }
    __syncthreads();                     // s_bmax init happens-before
    atomicMax(&s_bmax, lmax);
    __syncthreads();
    if (t == 0) atomicMax(gmax, s_bmax);
}

// ---- pass 3: requantize in place (int32 lin -> float q), nontemporal ----
__global__ void requant_kernel(f32x4* qout, const i32x4* lin, const int* gmax, int n4) {
    int i = blockIdx.x * 256 + threadIdx.x;
    if (i >= n4) return;
    float s = (float)(*gmax) / 127.0f;
    i32x4 v = __builtin_nontemporal_load(lin + i);
    f32x4 o;
    o.x = fminf(127.0f, fmaxf(-127.0f, rintf((float)v.x / s)));
    o.y = fminf(127.0f, fmaxf(-127.0f, rintf((float)v.y / s)));
    o.z = fminf(127.0f, fmaxf(-127.0f, rintf((float)v.z / s)));
    o.w = fminf(127.0f, fmaxf(-127.0f, rintf((float)v.w / s)));
    __builtin_nontemporal_store(o, qout + i);
}

// ---- pass 4: out_scale[b] = s * x_scale[b] * w_scale; zero_point = 0 ----
__global__ void scale_kernel(float* __restrict__ out_scale, float* __restrict__ out_zp,
                             const float* __restrict__ x_scale,
                             const float* __restrict__ w_scale_p,
                             const int* gmax, int B) {
    int i = blockIdx.x * 256 + threadIdx.x;
    if (i >= B) return;
    float s = (float)(*gmax) / 127.0f;
    out_scale[i] = s * x_scale[i] * w_scale_p[0];
    out_zp[i] = 0.0f;
}

extern "C" void kernel_launch(void* const* d_in, const int* in_sizes, int n_in,
                              void* d_out, int out_size, void* d_ws, size_t ws_size,
                              hipStream_t stream) {
    const float* x_q     = (const float*)d_in[0];
    const float* x_scale = (const float*)d_in[1];
    const float* x_zp    = (const float*)d_in[2];
    const float* w_q     = (const float*)d_in[3];
    const float* w_scale = (const float*)d_in[4];
    const float* fp_bias = (const float*)d_in[5];

    const int B   = in_sizes[1];           // 8192
    const int IN  = in_sizes[0] / B;       // 4096
    const int OUT = in_sizes[5];           // 4096

    float* q         = (float*)d_out;
    float* out_scale = q + (size_t)B * OUT;
    float* out_zp    = out_scale + B;

    // workspace layout
    char* ws    = (char*)d_ws;
    int* gmax   = (int*)ws;
    char* x8t   = ws + 64;
    char* w8t   = x8t + (size_t)B * IN;
    int* rowsum = (int*)(w8t + (size_t)OUT * IN);
    size_t needed = 64 + (size_t)B * IN + (size_t)OUT * IN + (size_t)OUT * 4;
    if (ws_size < needed) return;  // would corrupt; fail loudly with zero output

    conv_x_kernel<<<(B / 128) * (IN / 64), 512, 0, stream>>>(x_q, x8t, gmax, IN);
    conv_w_kernel<<<(OUT / 128) * (IN / 64), 512, 0, stream>>>(w_q, w8t, IN);
    rowsum_kernel<<<OUT, 256, 0, stream>>>(w8t, rowsum, IN);

    int nblocks = (B / 128) * (OUT / 128);   // 2048
    gemm_i8_kernel<<<nblocks, 256, 0, stream>>>(x8t, w8t, rowsum, x_scale, x_zp, fp_bias,
                                                w_scale, (int*)q, gmax, OUT, IN);

    int n4q = (B * OUT) >> 2;
    requant_kernel<<<(n4q + 255) / 256, 256, 0, stream>>>((f32x4*)q, (const i32x4*)q, gmax, n4q);
    scale_kernel<<<(B + 255) / 256, 256, 0, stream>>>(out_scale, out_zp, x_scale, w_scale, gmax, B);
}

// Round 11
// 274.400 us; speedup vs baseline: 1.1248x; 1.1248x over previous
//
#include <hip/hip_runtime.h>
#include <hip/hip_bf16.h>

// QuantizedLinear: q = clip(round(lin/s)), s = max|lin|/127,
// lin = (x_q - x_zp) @ w_q^T + round(fp_bias / (w_scale*x_scale))
// Exact-integer path: x8 = x_q-128 (int8), w8 = w_q (int8),
// lin = x8@w8^T + (128 - x_zp[b])*rowsum(w) + qbias   (all int32, exact)
//
// GEMM (r11): r10's no-LDS fragment-direct design + latency fixes.
// r10's VGPR_Count=72 proved the compiler SANK the prefetch loads to their
// uses (acc alone is 64 regs; two operand sets would be ~136 total) -- every
// tile exposed full L2/LLC load latency, which explains the 213-243us
// invariant across all 10 structures. Fixes:
// (1) sched_barrier(0) after each load-issue group pins true dist-1 pipelining
//     (loads in flight across the MFMA burst); VGPR should rise to ~150.
// (2) chunk=XCD 16x16 block mapping: concurrent blocks per XCD share 16
//     A-slabs + ~6 B-slabs (~11MB) -> higher L2/LLC hit rate.

typedef int i32x4 __attribute__((ext_vector_type(4)));
typedef float f32x4 __attribute__((ext_vector_type(4)));

// ---- pass 1a: x8t = fragment-ordered (x_q - 128); zero gmax ----
// block = (bm, kt): 512 thr, thread t=(m*64+l) -> 16B of sub-frag (bm,kt,m)
__global__ void conv_x_kernel(const float* __restrict__ xq, char* __restrict__ x8t,
                              int* gmax, int IN) {
    const int nkt = IN >> 6;
    const int bm = blockIdx.x / nkt, kt = blockIdx.x % nkt;
    const int t = threadIdx.x;
    const int m = t >> 6, l = t & 63;
    if (blockIdx.x == 0 && t == 0) *gmax = 0;
    const int row = bm * 128 + m * 16 + (l & 15);
    const int col = kt * 64 + (l >> 4) * 16;
    const float4* src = (const float4*)(xq + (size_t)row * IN + col);
    uint out[4];
    #pragma unroll
    for (int c = 0; c < 4; ++c) {
        float4 v = src[c];
        out[c] = (((int)v.x - 128) & 255) | ((((int)v.y - 128) & 255) << 8) |
                 ((((int)v.z - 128) & 255) << 16) | ((((int)v.w - 128) & 255) << 24);
    }
    *(uint4*)(x8t + ((size_t)blockIdx.x * 8 + m) * 1024 + l * 16) =
        make_uint4(out[0], out[1], out[2], out[3]);
}

// ---- pass 1b: w8t = fragment-ordered w_q ----
__global__ void conv_w_kernel(const float* __restrict__ wq, char* __restrict__ w8t,
                              int IN) {
    const int nkt = IN >> 6;
    const int bn = blockIdx.x / nkt, kt = blockIdx.x % nkt;
    const int t = threadIdx.x;
    const int m = t >> 6, l = t & 63;
    const int row = bn * 128 + m * 16 + (l & 15);
    const int col = kt * 64 + (l >> 4) * 16;
    const float4* src = (const float4*)(wq + (size_t)row * IN + col);
    uint out[4];
    #pragma unroll
    for (int c = 0; c < 4; ++c) {
        float4 v = src[c];
        out[c] = (((int)v.x) & 255) | ((((int)v.y) & 255) << 8) |
                 ((((int)v.z) & 255) << 16) | ((((int)v.w) & 255) << 24);
    }
    *(uint4*)(w8t + ((size_t)blockIdx.x * 8 + m) * 1024 + l * 16) =
        make_uint4(out[0], out[1], out[2], out[3]);
}

// ---- pass 1c: rowsum[r] = sum_k w8t row r (reads fragment layout) ----
__global__ void rowsum_kernel(const char* __restrict__ w8t, int* __restrict__ rowsum,
                              int IN) {
    const int r = blockIdx.x;
    const int bn = r >> 7, n = (r >> 4) & 7, rl = r & 15;
    const int t = threadIdx.x;          // 256
    const int nkt = IN >> 6;
    int sum = 0;
    for (int idx = t; idx < nkt * 4; idx += 256) {
        const int kt = idx >> 2, cs = idx & 3;
        const int* p = (const int*)(w8t + (((size_t)bn * nkt + kt) * 8 + n) * 1024
                                    + (size_t)((cs << 4) | rl) * 16);
        #pragma unroll
        for (int k = 0; k < 4; ++k) {
            const int u = p[k];
            sum += ((int)(u << 24) >> 24) + ((int)(u << 16) >> 24) +
                   ((int)(u << 8) >> 24) + (u >> 24);
        }
    }
    #pragma unroll
    for (int msk = 32; msk; msk >>= 1) sum += __shfl_xor(sum, msk, 64);
    __shared__ int wsum[4];
    if ((t & 63) == 0) wsum[t >> 6] = sum;
    __syncthreads();
    if (t == 0) rowsum[r] = wsum[0] + wsum[1] + wsum[2] + wsum[3];
}

// ---- pass 2: int8 GEMM, 128x128 tile, fragment-direct, pinned dist-1 ----
__global__ __launch_bounds__(256, 3) void gemm_i8_kernel(
    const char* __restrict__ x8t, const char* __restrict__ w8t,
    const int* __restrict__ w_rowsum,
    const float* __restrict__ x_scale, const float* __restrict__ x_zp,
    const float* __restrict__ fp_bias, const float* __restrict__ w_scale_p,
    int* __restrict__ lin_out, int* gmax, int N, int K) {
    __shared__ int s_bmax;
    const int t = threadIdx.x;
    const int w = t >> 6, l = t & 63;
    if (t == 0) s_bmax = 0;

    // T1: XCD swizzle -> each XCD owns a contiguous swz chunk of 256
    const int nwg = gridDim.x;
    int swz = blockIdx.x;
    if ((nwg & 7) == 0) { const int cpx = nwg >> 3; swz = (swz & 7) * cpx + (swz >> 3); }
    // chunk(=XCD) covers a 16x16 square of the 64(tm) x 32(tn) tile grid:
    // concurrent blocks share 16 A-slabs + ~6 B-slabs (~11MB) -> L2/LLC hits.
    const int chunk = swz >> 8, local = swz & 255;
    const int cm = chunk >> 1, cn = chunk & 1;
    const int tm = cm * 16 + (local & 15);
    const int tn = cn * 16 + (local >> 4);

    const int nt = K >> 6;             // 64B K-tiles (64); even
    const int lane_lo = l & 15, lane_hi = l >> 4;
    const int wm = w >> 1, wn = w & 1; // 2 x 2 wave grid

    // fragment bases: sub-frag (tile j, idx wm*4+m) at ((tm*nt + j)*8 + wm*4+m)*1024
    const char* pa = x8t + ((size_t)tm * nt * 8 + (size_t)wm * 4) * 1024 + l * 16;
    const char* pb = w8t + ((size_t)tn * nt * 8 + (size_t)wn * 4) * 1024 + l * 16;

    i32x4 acc[4][4] = {};
    i32x4 aA[4], bA[4], aB[4], bB[4];

    #define LDA(dst, j) { const char* p_ = pa + (size_t)(j) * 8192;                 \
        dst[0] = *(const i32x4*)(p_);        dst[1] = *(const i32x4*)(p_ + 1024);   \
        dst[2] = *(const i32x4*)(p_ + 2048); dst[3] = *(const i32x4*)(p_ + 3072); }
    #define LDB(dst, j) { const char* p_ = pb + (size_t)(j) * 8192;                 \
        dst[0] = *(const i32x4*)(p_);        dst[1] = *(const i32x4*)(p_ + 1024);   \
        dst[2] = *(const i32x4*)(p_ + 2048); dst[3] = *(const i32x4*)(p_ + 3072); }
    #define MFMA16(a_, b_) {                                                        \
        __builtin_amdgcn_s_setprio(1);                                              \
        _Pragma("unroll")                                                           \
        for (int m = 0; m < 4; ++m)                                                 \
            _Pragma("unroll")                                                       \
            for (int n = 0; n < 4; ++n)                                             \
                acc[m][n] = __builtin_amdgcn_mfma_i32_16x16x64_i8(a_[m], b_[n],     \
                                                                  acc[m][n], 0,0,0);\
        __builtin_amdgcn_s_setprio(0); }
    // PIN: loads issued before this point may not sink past it (r10: compiler
    // sank all prefetches -> VGPR 72 -> every tile exposed full load latency)
    #define PIN() __builtin_amdgcn_sched_barrier(0)

    LDA(aA, 0); LDB(bA, 0);
    for (int j = 0; j < nt; j += 2) {
        LDA(aB, j + 1); LDB(bB, j + 1);    // issue odd-tile loads
        PIN();
        MFMA16(aA, bA);                    // consume even tile (in flight 1 burst)
        if (j + 2 < nt) { LDA(aA, j + 2); LDB(bA, j + 2); }  // issue next even
        PIN();
        MFMA16(aB, bB);                    // consume odd tile
    }
    #undef LDA
    #undef LDB
    #undef MFMA16
    #undef PIN

    // ---- epilogue: lin = acc + z*rowsum + qbias; track max|lin|.
    // lin stores NONTEMPORAL (output stream should not evict operand panels).
    const float ws = *w_scale_p;
    const int rowg0 = tm * 128 + wm * 64 + lane_hi * 4;   // + m*16 + r
    const int colg0 = tn * 128 + wn * 64 + lane_lo;       // + n*16
    float fbws[4]; int wrs[4];
    #pragma unroll
    for (int n = 0; n < 4; ++n) {
        fbws[n] = fp_bias[colg0 + n * 16] / ws;
        wrs[n] = w_rowsum[colg0 + n * 16];
    }
    int lmax = 0;
    #pragma unroll
    for (int m = 0; m < 4; ++m) {
        #pragma unroll
        for (int r = 0; r < 4; ++r) {
            const int row = rowg0 + m * 16 + r;
            const float rxs = 1.0f / x_scale[row];
            const int zz = 128 - (int)x_zp[row];
            int* orow = lin_out + (size_t)row * N + colg0;
            #pragma unroll
            for (int n = 0; n < 4; ++n) {
                const int qb = (int)rintf(fbws[n] * rxs);
                const int lin = acc[m][n][r] + zz * wrs[n] + qb;
                const int a = lin < 0 ? -lin : lin;
                lmax = a > lmax ? a : lmax;
                __builtin_nontemporal_store(lin, orow + n * 16);
            }
        }
    }
    __syncthreads();                     // s_bmax init happens-before
    atomicMax(&s_bmax, lmax);
    __syncthreads();
    if (t == 0) atomicMax(gmax, s_bmax);
}

// ---- pass 3: requantize in place (int32 lin -> float q), nontemporal ----
__global__ void requant_kernel(f32x4* qout, const i32x4* lin, const int* gmax, int n4) {
    int i = blockIdx.x * 256 + threadIdx.x;
    if (i >= n4) return;
    float s = (float)(*gmax) / 127.0f;
    i32x4 v = __builtin_nontemporal_load(lin + i);
    f32x4 o;
    o.x = fminf(127.0f, fmaxf(-127.0f, rintf((float)v.x / s)));
    o.y = fminf(127.0f, fmaxf(-127.0f, rintf((float)v.y / s)));
    o.z = fminf(127.0f, fmaxf(-127.0f, rintf((float)v.z / s)));
    o.w = fminf(127.0f, fmaxf(-127.0f, rintf((float)v.w / s)));
    __builtin_nontemporal_store(o, qout + i);
}

// ---- pass 4: out_scale[b] = s * x_scale[b] * w_scale; zero_point = 0 ----
__global__ void scale_kernel(float* __restrict__ out_scale, float* __restrict__ out_zp,
                             const float* __restrict__ x_scale,
                             const float* __restrict__ w_scale_p,
                             const int* gmax, int B) {
    int i = blockIdx.x * 256 + threadIdx.x;
    if (i >= B) return;
    float s = (float)(*gmax) / 127.0f;
    out_scale[i] = s * x_scale[i] * w_scale_p[0];
    out_zp[i] = 0.0f;
}

extern "C" void kernel_launch(void* const* d_in, const int* in_sizes, int n_in,
                              void* d_out, int out_size, void* d_ws, size_t ws_size,
                              hipStream_t stream) {
    const float* x_q     = (const float*)d_in[0];
    const float* x_scale = (const float*)d_in[1];
    const float* x_zp    = (const float*)d_in[2];
    const float* w_q     = (const float*)d_in[3];
    const float* w_scale = (const float*)d_in[4];
    const float* fp_bias = (const float*)d_in[5];

    const int B   = in_sizes[1];           // 8192
    const int IN  = in_sizes[0] / B;       // 4096
    const int OUT = in_sizes[5];           // 4096

    float* q         = (float*)d_out;
    float* out_scale = q + (size_t)B * OUT;
    float* out_zp    = out_scale + B;

    // workspace layout
    char* ws    = (char*)d_ws;
    int* gmax   = (int*)ws;
    char* x8t   = ws + 64;
    char* w8t   = x8t + (size_t)B * IN;
    int* rowsum = (int*)(w8t + (size_t)OUT * IN);
    size_t needed = 64 + (size_t)B * IN + (size_t)OUT * IN + (size_t)OUT * 4;
    if (ws_size < needed) return;  // would corrupt; fail loudly with zero output

    conv_x_kernel<<<(B / 128) * (IN / 64), 512, 0, stream>>>(x_q, x8t, gmax, IN);
    conv_w_kernel<<<(OUT / 128) * (IN / 64), 512, 0, stream>>>(w_q, w8t, IN);
    rowsum_kernel<<<OUT, 256, 0, stream>>>(w8t, rowsum, IN);

    int nblocks = (B / 128) * (OUT / 128);   // 2048
    gemm_i8_kernel<<<nblocks, 256, 0, stream>>>(x8t, w8t, rowsum, x_scale, x_zp, fp_bias,
                                                w_scale, (int*)q, gmax, OUT, IN);

    int n4q = (B * OUT) >> 2;
    requant_kernel<<<(n4q + 255) / 256, 256, 0, stream>>>((f32x4*)q, (const i32x4*)q, gmax, n4q);
    scale_kernel<<<(B + 255) / 256, 256, 0, stream>>>(out_scale, out_zp, x_scale, w_scale, gmax, B);
}